// Round 1
// baseline (1254.647 us; speedup 1.0000x reference)
//
#include <hip/hip_runtime.h>
#include <hip/hip_bf16.h>

#define NN 100000
#define NE 1600000
#define DD 128

// ---------------- CSR build ----------------

__global__ void count_kernel(const int* __restrict__ col, int* __restrict__ counts, int E) {
    int i = blockIdx.x * 256 + threadIdx.x;
    if (i < E) atomicAdd(&counts[col[i]], 1);
}

__global__ void scan_partial(const int* __restrict__ counts, int* __restrict__ blockSums, int n) {
    __shared__ int red[256];
    int base = blockIdx.x * 1024;
    int s = 0;
#pragma unroll
    for (int i = 0; i < 4; ++i) {
        int idx = base + i * 256 + threadIdx.x;
        if (idx < n) s += counts[idx];
    }
    red[threadIdx.x] = s;
    __syncthreads();
    for (int off = 128; off > 0; off >>= 1) {
        if (threadIdx.x < off) red[threadIdx.x] += red[threadIdx.x + off];
        __syncthreads();
    }
    if (threadIdx.x == 0) blockSums[blockIdx.x] = red[0];
}

// single block: exclusive-scan blockSums in place; write offsets[NN] = total
__global__ void scan_sums(int* __restrict__ blockSums, int nb, int* __restrict__ offsets) {
    __shared__ int s[128];
    int tid = threadIdx.x;
    int v = (tid < nb) ? blockSums[tid] : 0;
    s[tid] = v;
    __syncthreads();
    for (int off = 1; off < 128; off <<= 1) {
        int t = (tid >= off) ? s[tid - off] : 0;
        __syncthreads();
        s[tid] += t;
        __syncthreads();
    }
    if (tid < nb) blockSums[tid] = s[tid] - v;  // exclusive
    if (tid == 0) offsets[NN] = s[nb - 1];      // grand total = E
}

__global__ void scan_final(const int* __restrict__ counts, const int* __restrict__ blockSums,
                           int* __restrict__ offsets, int* __restrict__ cursor, int n) {
    __shared__ int red[256];
    int tid = threadIdx.x;
    int idx0 = blockIdx.x * 1024 + tid * 4;
    int v[4];
#pragma unroll
    for (int i = 0; i < 4; ++i) {
        int idx = idx0 + i;
        v[i] = (idx < n) ? counts[idx] : 0;
    }
    int tsum = v[0] + v[1] + v[2] + v[3];
    red[tid] = tsum;
    __syncthreads();
    for (int off = 1; off < 256; off <<= 1) {
        int t = (tid >= off) ? red[tid - off] : 0;
        __syncthreads();
        red[tid] += t;
        __syncthreads();
    }
    int run = blockSums[blockIdx.x] + (red[tid] - tsum);
#pragma unroll
    for (int i = 0; i < 4; ++i) {
        int idx = idx0 + i;
        if (idx < n) { offsets[idx] = run; cursor[idx] = run; }
        run += v[i];
    }
}

__global__ void fill_kernel(const int* __restrict__ row, const int* __restrict__ col,
                            int* __restrict__ cursor, int* __restrict__ csr_src, int E) {
    int i = blockIdx.x * 256 + threadIdx.x;
    if (i < E) {
        int p = atomicAdd(&cursor[col[i]], 1);
        csr_src[p] = row[i];
    }
}

__global__ void dis_kernel(const int* __restrict__ counts, float* __restrict__ dis, int n) {
    int i = blockIdx.x * 256 + threadIdx.x;
    if (i < n) dis[i] = rsqrtf((float)(counts[i] + 1));  // +1 self-loop; deg >= 1 always
}

// ---------------- per-layer kernels ----------------

// Y[m][n] = sum_k X[m][k] * W[k][n];  M=100000 (32 | M), K=N=128.
// Block: 256 threads, 32 rows. W fully staged in LDS (64 KB). Thread tile 2x8.
__global__ __launch_bounds__(256) void gemm_kernel(const float* __restrict__ X,
                                                   const float* __restrict__ W,
                                                   float* __restrict__ Y) {
    __shared__ float wlds[DD * DD];  // 64 KB
#pragma unroll
    for (int i = 0; i < 16; ++i) {
        int idx = i * 1024 + threadIdx.x * 4;
        *(float4*)&wlds[idx] = *(const float4*)&W[idx];
    }
    __syncthreads();

    const int tc = threadIdx.x & 15;
    const int tr = threadIdx.x >> 4;
    const int c0 = tc * 8;
    const int r0 = blockIdx.x * 32 + tr * 2;

    float acc0[8] = {0, 0, 0, 0, 0, 0, 0, 0};
    float acc1[8] = {0, 0, 0, 0, 0, 0, 0, 0};
    const float* x0 = X + (size_t)r0 * DD;
    const float* x1 = x0 + DD;

    for (int kk = 0; kk < DD; kk += 4) {
        float4 xa = *(const float4*)(x0 + kk);
        float4 xb = *(const float4*)(x1 + kk);
        const float xs0[4] = {xa.x, xa.y, xa.z, xa.w};
        const float xs1[4] = {xb.x, xb.y, xb.z, xb.w};
#pragma unroll
        for (int j = 0; j < 4; ++j) {
            const float* wrow = &wlds[(kk + j) * DD + c0];
            float4 w0 = *(const float4*)wrow;
            float4 w1 = *(const float4*)(wrow + 4);
            acc0[0] += xs0[j] * w0.x;  acc0[1] += xs0[j] * w0.y;
            acc0[2] += xs0[j] * w0.z;  acc0[3] += xs0[j] * w0.w;
            acc0[4] += xs0[j] * w1.x;  acc0[5] += xs0[j] * w1.y;
            acc0[6] += xs0[j] * w1.z;  acc0[7] += xs0[j] * w1.w;
            acc1[0] += xs1[j] * w0.x;  acc1[1] += xs1[j] * w0.y;
            acc1[2] += xs1[j] * w0.z;  acc1[3] += xs1[j] * w0.w;
            acc1[4] += xs1[j] * w1.x;  acc1[5] += xs1[j] * w1.y;
            acc1[6] += xs1[j] * w1.z;  acc1[7] += xs1[j] * w1.w;
        }
    }

    float* y0 = Y + (size_t)r0 * DD + c0;
    float* y1 = y0 + DD;
    *(float4*)y0       = make_float4(acc0[0], acc0[1], acc0[2], acc0[3]);
    *(float4*)(y0 + 4) = make_float4(acc0[4], acc0[5], acc0[6], acc0[7]);
    *(float4*)y1       = make_float4(acc1[0], acc1[1], acc1[2], acc1[3]);
    *(float4*)(y1 + 4) = make_float4(acc1[4], acc1[5], acc1[6], acc1[7]);
}

// out[v][d] = relu( dis[v]*( sum_{e in(v)} lin[src][d]*dis[src] + dis[v]*lin[v][d] ) + b[d] )
// block = 256 threads = 2 nodes x 128 dims (each wave uniform in v)
__global__ __launch_bounds__(256) void agg_kernel(const float* __restrict__ lin,
                                                  const int* __restrict__ offsets,
                                                  const int* __restrict__ csr_src,
                                                  const float* __restrict__ dis,
                                                  const float* __restrict__ bias,
                                                  float* __restrict__ out) {
    const int v = blockIdx.x * 2 + (threadIdx.x >> 7);
    const int d = threadIdx.x & 127;
    const int start = offsets[v];
    const int end = offsets[v + 1];
    float acc = 0.f;
    for (int e = start; e < end; ++e) {
        int s = csr_src[e];
        acc += lin[(size_t)s * DD + d] * dis[s];
    }
    const float dv = dis[v];
    const float self = lin[(size_t)v * DD + d];
    float r = dv * (acc + dv * self) + bias[d];
    out[(size_t)v * DD + d] = fmaxf(r, 0.f);
}

// ---------------- launch ----------------

extern "C" void kernel_launch(void* const* d_in, const int* in_sizes, int n_in,
                              void* d_out, int out_size, void* d_ws, size_t ws_size,
                              hipStream_t stream) {
    const float* x   = (const float*)d_in[0];
    const int*   ei  = (const int*)d_in[1];
    const float* Ws  = (const float*)d_in[2];
    const float* bs  = (const float*)d_in[3];
    float* out = (float*)d_out;

    const int E = NE;
    const int* row = ei;
    const int* col = ei + E;

    char* ws = (char*)d_ws;
    float* lin      = (float*)(ws + 0);          // 12.8M f32 = 51,200,000 B
    float* dis      = (float*)(ws + 51200000);   // 100k f32
    int*   counts   = (int*)  (ws + 51600000);   // 100k i32
    int*   cursor   = (int*)  (ws + 52000000);   // 100k i32
    int*   offsets  = (int*)  (ws + 52400000);   // 100k+1 i32
    int*   csr_src  = (int*)  (ws + 52800016);   // 1.6M i32
    int*   blockSums= (int*)  (ws + 59200016);   // 128 i32

    hipMemsetAsync(counts, 0, NN * sizeof(int), stream);
    count_kernel<<<(E + 255) / 256, 256, 0, stream>>>(col, counts, E);

    const int nb = (NN + 1023) / 1024;  // 98
    scan_partial<<<nb, 256, 0, stream>>>(counts, blockSums, NN);
    scan_sums<<<1, 128, 0, stream>>>(blockSums, nb, offsets);
    scan_final<<<nb, 256, 0, stream>>>(counts, blockSums, offsets, cursor, NN);
    dis_kernel<<<(NN + 255) / 256, 256, 0, stream>>>(counts, dis, NN);
    fill_kernel<<<(E + 255) / 256, 256, 0, stream>>>(row, col, cursor, csr_src, E);

    for (int l = 0; l < 3; ++l) {
        const float* hin = (l == 0) ? x : out;
        gemm_kernel<<<NN / 32, 256, 0, stream>>>(hin, Ws + (size_t)l * DD * DD, lin);
        agg_kernel<<<NN / 2, 256, 0, stream>>>(lin, offsets, csr_src, dis, bs + (size_t)l * DD, out);
    }
}

// Round 2
// 726.757 us; speedup vs baseline: 1.7264x; 1.7264x over previous
//
#include <hip/hip_runtime.h>
#include <hip/hip_bf16.h>

#define NN 100000
#define NE 1600000
#define DD 128

// ---------------- CSR build ----------------

__global__ void count_kernel(const int* __restrict__ col, int* __restrict__ counts, int E) {
    int i = blockIdx.x * 256 + threadIdx.x;
    if (i < E) atomicAdd(&counts[col[i]], 1);
}

__global__ void scan_partial(const int* __restrict__ counts, int* __restrict__ blockSums, int n) {
    __shared__ int red[256];
    int base = blockIdx.x * 1024;
    int s = 0;
#pragma unroll
    for (int i = 0; i < 4; ++i) {
        int idx = base + i * 256 + threadIdx.x;
        if (idx < n) s += counts[idx];
    }
    red[threadIdx.x] = s;
    __syncthreads();
    for (int off = 128; off > 0; off >>= 1) {
        if (threadIdx.x < off) red[threadIdx.x] += red[threadIdx.x + off];
        __syncthreads();
    }
    if (threadIdx.x == 0) blockSums[blockIdx.x] = red[0];
}

// single block: exclusive-scan blockSums in place; write offsets[NN] = total
__global__ void scan_sums(int* __restrict__ blockSums, int nb, int* __restrict__ offsets) {
    __shared__ int s[128];
    int tid = threadIdx.x;
    int v = (tid < nb) ? blockSums[tid] : 0;
    s[tid] = v;
    __syncthreads();
    for (int off = 1; off < 128; off <<= 1) {
        int t = (tid >= off) ? s[tid - off] : 0;
        __syncthreads();
        s[tid] += t;
        __syncthreads();
    }
    if (tid < nb) blockSums[tid] = s[tid] - v;  // exclusive
    if (tid == 0) offsets[NN] = s[nb - 1];      // grand total = E
}

__global__ void scan_final(const int* __restrict__ counts, const int* __restrict__ blockSums,
                           int* __restrict__ offsets, int* __restrict__ cursor, int n) {
    __shared__ int red[256];
    int tid = threadIdx.x;
    int idx0 = blockIdx.x * 1024 + tid * 4;
    int v[4];
#pragma unroll
    for (int i = 0; i < 4; ++i) {
        int idx = idx0 + i;
        v[i] = (idx < n) ? counts[idx] : 0;
    }
    int tsum = v[0] + v[1] + v[2] + v[3];
    red[tid] = tsum;
    __syncthreads();
    for (int off = 1; off < 256; off <<= 1) {
        int t = (tid >= off) ? red[tid - off] : 0;
        __syncthreads();
        red[tid] += t;
        __syncthreads();
    }
    int run = blockSums[blockIdx.x] + (red[tid] - tsum);
#pragma unroll
    for (int i = 0; i < 4; ++i) {
        int idx = idx0 + i;
        if (idx < n) { offsets[idx] = run; cursor[idx] = run; }
        run += v[i];
    }
}

__global__ void fill_kernel(const int* __restrict__ row, const int* __restrict__ col,
                            int* __restrict__ cursor, int* __restrict__ csr_src, int E) {
    int i = blockIdx.x * 256 + threadIdx.x;
    if (i < E) {
        int p = atomicAdd(&cursor[col[i]], 1);
        csr_src[p] = row[i];
    }
}

__global__ void dis_kernel(const int* __restrict__ counts, float* __restrict__ dis, int n) {
    int i = blockIdx.x * 256 + threadIdx.x;
    if (i < n) dis[i] = rsqrtf((float)(counts[i] + 1));  // +1 self-loop; deg >= 1 always
}

// ---------------- per-layer kernels ----------------

// Y[r][c] = (sum_k X[r][k] * W[k][c]) * dis[r]   (pre-scaled by source dis)
// Block: 256 threads, 64 rows (4 rows/thread x 8 cols). W fully staged in LDS.
__global__ __launch_bounds__(256) void gemm_kernel(const float* __restrict__ X,
                                                   const float* __restrict__ W,
                                                   const float* __restrict__ dis,
                                                   float* __restrict__ Y) {
    __shared__ float wlds[DD * DD];  // 64 KB
#pragma unroll
    for (int i = 0; i < 16; ++i) {
        int idx = i * 1024 + threadIdx.x * 4;
        *(float4*)&wlds[idx] = *(const float4*)&W[idx];
    }
    __syncthreads();

    const int tc = threadIdx.x & 15;   // 16 col-groups x 8 cols
    const int tr = threadIdx.x >> 4;   // 16 row-groups x 4 rows
    const int c0 = tc * 8;
    const int r0 = blockIdx.x * 64 + tr * 4;

    float acc[4][8] = {};
    // clamp rows for loads (last block has 32 valid rows); stores are guarded
    int rr[4];
#pragma unroll
    for (int r = 0; r < 4; ++r) rr[r] = min(r0 + r, NN - 1);

    for (int kk = 0; kk < DD; kk += 4) {
        float xs[4][4];
#pragma unroll
        for (int r = 0; r < 4; ++r) {
            float4 xv = *(const float4*)(X + (size_t)rr[r] * DD + kk);
            xs[r][0] = xv.x; xs[r][1] = xv.y; xs[r][2] = xv.z; xs[r][3] = xv.w;
        }
#pragma unroll
        for (int j = 0; j < 4; ++j) {
            const float* wrow = &wlds[(kk + j) * DD + c0];
            float4 w0 = *(const float4*)wrow;
            float4 w1 = *(const float4*)(wrow + 4);
#pragma unroll
            for (int r = 0; r < 4; ++r) {
                acc[r][0] += xs[r][j] * w0.x;  acc[r][1] += xs[r][j] * w0.y;
                acc[r][2] += xs[r][j] * w0.z;  acc[r][3] += xs[r][j] * w0.w;
                acc[r][4] += xs[r][j] * w1.x;  acc[r][5] += xs[r][j] * w1.y;
                acc[r][6] += xs[r][j] * w1.z;  acc[r][7] += xs[r][j] * w1.w;
            }
        }
    }

#pragma unroll
    for (int r = 0; r < 4; ++r) {
        int row = r0 + r;
        if (row < NN) {
            float dsr = dis[row];
            float* y = Y + (size_t)row * DD + c0;
            *(float4*)y       = make_float4(acc[r][0] * dsr, acc[r][1] * dsr,
                                            acc[r][2] * dsr, acc[r][3] * dsr);
            *(float4*)(y + 4) = make_float4(acc[r][4] * dsr, acc[r][5] * dsr,
                                            acc[r][6] * dsr, acc[r][7] * dsr);
        }
    }
}

// out[v][d] = relu( dis[v]*( sum_{e in(v)} lin2[src][d] + lin2[v][d] ) + b[d] )
// where lin2 is pre-scaled by dis[src]. One wave per node; lane holds float2.
__global__ __launch_bounds__(256) void agg_kernel(const float* __restrict__ lin2,
                                                  const int* __restrict__ offsets,
                                                  const int* __restrict__ csr_src,
                                                  const float* __restrict__ dis,
                                                  const float* __restrict__ bias,
                                                  float* __restrict__ out) {
    const int wave = threadIdx.x >> 6;
    const int lane = threadIdx.x & 63;
    const int v = blockIdx.x * 4 + wave;

    const int start = offsets[v];
    const int end   = offsets[v + 1];
    const int n     = end - start;
    const int nv    = n < 64 ? n : 64;

    const float2* lp = (const float2*)lin2;   // row stride = 64 float2

    // one coalesced load covers the whole edge list for deg<=64
    int idxv = 0;
    if (lane < nv) idxv = csr_src[start + lane];

    // start self/bias/dis loads early
    const float dv = dis[v];
    float2 self = lp[(size_t)v * 64 + lane];
    float2 b    = ((const float2*)bias)[lane];

    float accx = 0.f, accy = 0.f;
    int k = 0;
    for (; k + 8 <= nv; k += 8) {
        int s0 = __shfl(idxv, k + 0);
        int s1 = __shfl(idxv, k + 1);
        int s2 = __shfl(idxv, k + 2);
        int s3 = __shfl(idxv, k + 3);
        int s4 = __shfl(idxv, k + 4);
        int s5 = __shfl(idxv, k + 5);
        int s6 = __shfl(idxv, k + 6);
        int s7 = __shfl(idxv, k + 7);
        float2 a0 = lp[(size_t)s0 * 64 + lane];
        float2 a1 = lp[(size_t)s1 * 64 + lane];
        float2 a2 = lp[(size_t)s2 * 64 + lane];
        float2 a3 = lp[(size_t)s3 * 64 + lane];
        float2 a4 = lp[(size_t)s4 * 64 + lane];
        float2 a5 = lp[(size_t)s5 * 64 + lane];
        float2 a6 = lp[(size_t)s6 * 64 + lane];
        float2 a7 = lp[(size_t)s7 * 64 + lane];
        accx += a0.x + a1.x + a2.x + a3.x + a4.x + a5.x + a6.x + a7.x;
        accy += a0.y + a1.y + a2.y + a3.y + a4.y + a5.y + a6.y + a7.y;
    }
    for (; k + 4 <= nv; k += 4) {
        int s0 = __shfl(idxv, k + 0);
        int s1 = __shfl(idxv, k + 1);
        int s2 = __shfl(idxv, k + 2);
        int s3 = __shfl(idxv, k + 3);
        float2 a0 = lp[(size_t)s0 * 64 + lane];
        float2 a1 = lp[(size_t)s1 * 64 + lane];
        float2 a2 = lp[(size_t)s2 * 64 + lane];
        float2 a3 = lp[(size_t)s3 * 64 + lane];
        accx += a0.x + a1.x + a2.x + a3.x;
        accy += a0.y + a1.y + a2.y + a3.y;
    }
    for (; k < nv; ++k) {
        int s = __shfl(idxv, k);
        float2 a = lp[(size_t)s * 64 + lane];
        accx += a.x; accy += a.y;
    }
    // rare deg>64 fallback
    for (int e = start + 64; e < end; ++e) {
        int s = csr_src[e];
        float2 a = lp[(size_t)s * 64 + lane];
        accx += a.x; accy += a.y;
    }

    float rx = dv * (accx + self.x) + b.x;
    float ry = dv * (accy + self.y) + b.y;
    float2 o;
    o.x = fmaxf(rx, 0.f);
    o.y = fmaxf(ry, 0.f);
    ((float2*)out)[(size_t)v * 64 + lane] = o;
}

// ---------------- launch ----------------

extern "C" void kernel_launch(void* const* d_in, const int* in_sizes, int n_in,
                              void* d_out, int out_size, void* d_ws, size_t ws_size,
                              hipStream_t stream) {
    const float* x   = (const float*)d_in[0];
    const int*   ei  = (const int*)d_in[1];
    const float* Ws  = (const float*)d_in[2];
    const float* bs  = (const float*)d_in[3];
    float* out = (float*)d_out;

    const int E = NE;
    const int* row = ei;
    const int* col = ei + E;

    char* ws = (char*)d_ws;
    float* lin      = (float*)(ws + 0);          // 12.8M f32 = 51,200,000 B
    float* dis      = (float*)(ws + 51200000);   // 100k f32
    int*   counts   = (int*)  (ws + 51600000);   // 100k i32
    int*   cursor   = (int*)  (ws + 52000000);   // 100k i32
    int*   offsets  = (int*)  (ws + 52400000);   // 100k+1 i32
    int*   csr_src  = (int*)  (ws + 52800016);   // 1.6M i32
    int*   blockSums= (int*)  (ws + 59200016);   // 128 i32

    hipMemsetAsync(counts, 0, NN * sizeof(int), stream);
    count_kernel<<<(E + 255) / 256, 256, 0, stream>>>(col, counts, E);

    const int nb = (NN + 1023) / 1024;  // 98
    scan_partial<<<nb, 256, 0, stream>>>(counts, blockSums, NN);
    scan_sums<<<1, 128, 0, stream>>>(blockSums, nb, offsets);
    scan_final<<<nb, 256, 0, stream>>>(counts, blockSums, offsets, cursor, NN);
    dis_kernel<<<(NN + 255) / 256, 256, 0, stream>>>(counts, dis, NN);
    fill_kernel<<<(E + 255) / 256, 256, 0, stream>>>(row, col, cursor, csr_src, E);

    for (int l = 0; l < 3; ++l) {
        const float* hin = (l == 0) ? x : out;
        gemm_kernel<<<(NN + 63) / 64, 256, 0, stream>>>(hin, Ws + (size_t)l * DD * DD, dis, lin);
        agg_kernel<<<NN / 4, 256, 0, stream>>>(lin, offsets, csr_src, dis, bs + (size_t)l * DD, out);
    }
}

// Round 3
// 588.841 us; speedup vs baseline: 2.1307x; 1.2342x over previous
//
#include <hip/hip_runtime.h>
#include <hip/hip_bf16.h>

#define NN 100000
#define NE 1600000
#define DD 128
#define NBUK 196          // ceil(100000 / 512) buckets of 512 target nodes
#define F1_BLOCKS 256
#define F3_BLOCKS 256

// ---------------- CSR build (bucketed counting sort) ----------------

// F1: per-block LDS histogram over col>>9, accumulate to global bukCount
__global__ __launch_bounds__(256) void f1_bucket_count(const int* __restrict__ col,
                                                       int* __restrict__ bukCount) {
    __shared__ int hist[NBUK];
    for (int t = threadIdx.x; t < NBUK; t += 256) hist[t] = 0;
    __syncthreads();
    const int epb = (NE + F1_BLOCKS - 1) / F1_BLOCKS;       // 6250
    const int e0 = blockIdx.x * epb;
    const int e1 = min(e0 + epb, NE);
    for (int e = e0 + threadIdx.x; e < e1; e += 256)
        atomicAdd(&hist[col[e] >> 9], 1);
    __syncthreads();
    for (int t = threadIdx.x; t < NBUK; t += 256)
        if (hist[t]) atomicAdd(&bukCount[t], hist[t]);
}

// F2: single-block exclusive scan of bucket counts -> bukBase, bukCursor
__global__ void f2_bucket_scan(const int* __restrict__ bukCount,
                               int* __restrict__ bukBase,
                               int* __restrict__ bukCursor,
                               int* __restrict__ offsets) {
    __shared__ int s[256];
    const int t = threadIdx.x;
    int v = (t < NBUK) ? bukCount[t] : 0;
    s[t] = v;
    __syncthreads();
    for (int off = 1; off < 256; off <<= 1) {
        int tmp = (t >= off) ? s[t - off] : 0;
        __syncthreads();
        s[t] += tmp;
        __syncthreads();
    }
    int excl = s[t] - v;
    if (t < NBUK) { bukBase[t] = excl; bukCursor[t] = excl; }
    if (t == 255) { bukBase[NBUK] = s[255]; offsets[NN] = s[255]; }
}

// F3: scatter (row,col) into bucket-partitioned ebuf with block-claimed runs
__global__ __launch_bounds__(256) void f3_scatter(const int* __restrict__ row,
                                                  const int* __restrict__ col,
                                                  int* __restrict__ bukCursor,
                                                  int2* __restrict__ ebuf) {
    __shared__ int hist[NBUK];
    __shared__ int base[NBUK];
    __shared__ int rnk[NBUK];
    for (int t = threadIdx.x; t < NBUK; t += 256) { hist[t] = 0; rnk[t] = 0; }
    __syncthreads();
    const int epb = (NE + F3_BLOCKS - 1) / F3_BLOCKS;       // 6250
    const int e0 = blockIdx.x * epb;
    const int e1 = min(e0 + epb, NE);
    for (int e = e0 + threadIdx.x; e < e1; e += 256)
        atomicAdd(&hist[col[e] >> 9], 1);
    __syncthreads();
    for (int t = threadIdx.x; t < NBUK; t += 256)
        base[t] = hist[t] ? atomicAdd(&bukCursor[t], hist[t]) : 0;
    __syncthreads();
    for (int e = e0 + threadIdx.x; e < e1; e += 256) {
        int c = col[e];
        int b = c >> 9;
        int r = atomicAdd(&rnk[b], 1);
        ebuf[base[b] + r] = make_int2(row[e], c);
    }
}

// F4: one block per bucket. Count 512 cols in LDS, block-scan -> offsets + dis,
// then LDS-cursor scatter of csr_src into this bucket's contiguous region.
__global__ __launch_bounds__(256) void f4_finalize(const int2* __restrict__ ebuf,
                                                   const int* __restrict__ bukBase,
                                                   int* __restrict__ offsets,
                                                   float* __restrict__ dis,
                                                   int* __restrict__ csr_src) {
    __shared__ int cnt[512];
    __shared__ int cur[512];
    __shared__ int s[256];
    const int t = threadIdx.x;
    const int colBase = blockIdx.x << 9;
    const int ncols = min(512, NN - colBase);
    cnt[t] = 0; cnt[t + 256] = 0;
    __syncthreads();
    const int eb0 = bukBase[blockIdx.x];
    const int eb1 = bukBase[blockIdx.x + 1];
    for (int e = eb0 + t; e < eb1; e += 256)
        atomicAdd(&cnt[ebuf[e].y - colBase], 1);
    __syncthreads();
    // block scan over 512 counts (each thread owns pair 2t, 2t+1)
    const int c0 = cnt[2 * t], c1 = cnt[2 * t + 1];
    const int psum = c0 + c1;
    s[t] = psum;
    __syncthreads();
    for (int off = 1; off < 256; off <<= 1) {
        int tmp = (t >= off) ? s[t - off] : 0;
        __syncthreads();
        s[t] += tmp;
        __syncthreads();
    }
    const int exclPair = s[t] - psum;
    const int g0 = eb0 + exclPair;
    const int g1 = g0 + c0;
    cur[2 * t] = g0; cur[2 * t + 1] = g1;
    if (2 * t < ncols)     { offsets[colBase + 2 * t]     = g0; dis[colBase + 2 * t]     = rsqrtf((float)(c0 + 1)); }
    if (2 * t + 1 < ncols) { offsets[colBase + 2 * t + 1] = g1; dis[colBase + 2 * t + 1] = rsqrtf((float)(c1 + 1)); }
    __syncthreads();
    for (int e = eb0 + t; e < eb1; e += 256) {
        int2 rc = ebuf[e];
        int p = atomicAdd(&cur[rc.y - colBase], 1);
        csr_src[p] = rc.x;
    }
}

// ---------------- per-layer kernels ----------------

// Y[r][c] = (sum_k X[r][k] * W[k][c]) * dis[r]   (pre-scaled by source dis)
__global__ __launch_bounds__(256) void gemm_kernel(const float* __restrict__ X,
                                                   const float* __restrict__ W,
                                                   const float* __restrict__ dis,
                                                   float* __restrict__ Y) {
    __shared__ float wlds[DD * DD];  // 64 KB
#pragma unroll
    for (int i = 0; i < 16; ++i) {
        int idx = i * 1024 + threadIdx.x * 4;
        *(float4*)&wlds[idx] = *(const float4*)&W[idx];
    }
    __syncthreads();

    const int tc = threadIdx.x & 15;
    const int tr = threadIdx.x >> 4;
    const int c0 = tc * 8;
    const int r0 = blockIdx.x * 64 + tr * 4;

    float acc[4][8] = {};
    int rr[4];
#pragma unroll
    for (int r = 0; r < 4; ++r) rr[r] = min(r0 + r, NN - 1);

    for (int kk = 0; kk < DD; kk += 4) {
        float xs[4][4];
#pragma unroll
        for (int r = 0; r < 4; ++r) {
            float4 xv = *(const float4*)(X + (size_t)rr[r] * DD + kk);
            xs[r][0] = xv.x; xs[r][1] = xv.y; xs[r][2] = xv.z; xs[r][3] = xv.w;
        }
#pragma unroll
        for (int j = 0; j < 4; ++j) {
            const float* wrow = &wlds[(kk + j) * DD + c0];
            float4 w0 = *(const float4*)wrow;
            float4 w1 = *(const float4*)(wrow + 4);
#pragma unroll
            for (int r = 0; r < 4; ++r) {
                acc[r][0] += xs[r][j] * w0.x;  acc[r][1] += xs[r][j] * w0.y;
                acc[r][2] += xs[r][j] * w0.z;  acc[r][3] += xs[r][j] * w0.w;
                acc[r][4] += xs[r][j] * w1.x;  acc[r][5] += xs[r][j] * w1.y;
                acc[r][6] += xs[r][j] * w1.z;  acc[r][7] += xs[r][j] * w1.w;
            }
        }
    }

#pragma unroll
    for (int r = 0; r < 4; ++r) {
        int row = r0 + r;
        if (row < NN) {
            float dsr = dis[row];
            float* y = Y + (size_t)row * DD + c0;
            *(float4*)y       = make_float4(acc[r][0] * dsr, acc[r][1] * dsr,
                                            acc[r][2] * dsr, acc[r][3] * dsr);
            *(float4*)(y + 4) = make_float4(acc[r][4] * dsr, acc[r][5] * dsr,
                                            acc[r][6] * dsr, acc[r][7] * dsr);
        }
    }
}

// out[v][d] = relu( dis[v]*( sum_{e in(v)} lin2[src][d] + lin2[v][d] ) + b[d] )
__global__ __launch_bounds__(256) void agg_kernel(const float* __restrict__ lin2,
                                                  const int* __restrict__ offsets,
                                                  const int* __restrict__ csr_src,
                                                  const float* __restrict__ dis,
                                                  const float* __restrict__ bias,
                                                  float* __restrict__ out) {
    const int wave = threadIdx.x >> 6;
    const int lane = threadIdx.x & 63;
    const int v = blockIdx.x * 4 + wave;

    const int start = offsets[v];
    const int end   = offsets[v + 1];
    const int n     = end - start;
    const int nv    = n < 64 ? n : 64;

    const float2* lp = (const float2*)lin2;

    int idxv = 0;
    if (lane < nv) idxv = csr_src[start + lane];

    const float dv = dis[v];
    float2 self = lp[(size_t)v * 64 + lane];
    float2 b    = ((const float2*)bias)[lane];

    float accx = 0.f, accy = 0.f;
    int k = 0;
    for (; k + 8 <= nv; k += 8) {
        int s0 = __shfl(idxv, k + 0);
        int s1 = __shfl(idxv, k + 1);
        int s2 = __shfl(idxv, k + 2);
        int s3 = __shfl(idxv, k + 3);
        int s4 = __shfl(idxv, k + 4);
        int s5 = __shfl(idxv, k + 5);
        int s6 = __shfl(idxv, k + 6);
        int s7 = __shfl(idxv, k + 7);
        float2 a0 = lp[(size_t)s0 * 64 + lane];
        float2 a1 = lp[(size_t)s1 * 64 + lane];
        float2 a2 = lp[(size_t)s2 * 64 + lane];
        float2 a3 = lp[(size_t)s3 * 64 + lane];
        float2 a4 = lp[(size_t)s4 * 64 + lane];
        float2 a5 = lp[(size_t)s5 * 64 + lane];
        float2 a6 = lp[(size_t)s6 * 64 + lane];
        float2 a7 = lp[(size_t)s7 * 64 + lane];
        accx += a0.x + a1.x + a2.x + a3.x + a4.x + a5.x + a6.x + a7.x;
        accy += a0.y + a1.y + a2.y + a3.y + a4.y + a5.y + a6.y + a7.y;
    }
    for (; k + 4 <= nv; k += 4) {
        int s0 = __shfl(idxv, k + 0);
        int s1 = __shfl(idxv, k + 1);
        int s2 = __shfl(idxv, k + 2);
        int s3 = __shfl(idxv, k + 3);
        float2 a0 = lp[(size_t)s0 * 64 + lane];
        float2 a1 = lp[(size_t)s1 * 64 + lane];
        float2 a2 = lp[(size_t)s2 * 64 + lane];
        float2 a3 = lp[(size_t)s3 * 64 + lane];
        accx += a0.x + a1.x + a2.x + a3.x;
        accy += a0.y + a1.y + a2.y + a3.y;
    }
    for (; k < nv; ++k) {
        int s = __shfl(idxv, k);
        float2 a = lp[(size_t)s * 64 + lane];
        accx += a.x; accy += a.y;
    }
    for (int e = start + 64; e < end; ++e) {
        int s = csr_src[e];
        float2 a = lp[(size_t)s * 64 + lane];
        accx += a.x; accy += a.y;
    }

    float rx = dv * (accx + self.x) + b.x;
    float ry = dv * (accy + self.y) + b.y;
    float2 o;
    o.x = fmaxf(rx, 0.f);
    o.y = fmaxf(ry, 0.f);
    ((float2*)out)[(size_t)v * 64 + lane] = o;
}

// ---------------- launch ----------------

extern "C" void kernel_launch(void* const* d_in, const int* in_sizes, int n_in,
                              void* d_out, int out_size, void* d_ws, size_t ws_size,
                              hipStream_t stream) {
    const float* x   = (const float*)d_in[0];
    const int*   ei  = (const int*)d_in[1];
    const float* Ws  = (const float*)d_in[2];
    const float* bs  = (const float*)d_in[3];
    float* out = (float*)d_out;

    const int* row = ei;
    const int* col = ei + NE;

    char* ws = (char*)d_ws;
    float* lin       = (float*)(ws + 0);          // 51,200,000 B (ebuf aliases this)
    int2*  ebuf      = (int2*) (ws + 0);          // 1.6M int2 = 12,800,000 B (dead before gemm)
    float* dis       = (float*)(ws + 51200000);   // 400,000 B
    int*   offsets   = (int*)  (ws + 51600000);   // 400,004 B
    int*   csr_src   = (int*)  (ws + 52000016);   // 6,400,000 B
    int*   bukCount  = (int*)  (ws + 58400016);   // 784 B
    int*   bukBase   = (int*)  (ws + 58400800);   // 788 B
    int*   bukCursor = (int*)  (ws + 58401600);   // 784 B

    hipMemsetAsync(bukCount, 0, NBUK * sizeof(int), stream);
    f1_bucket_count<<<F1_BLOCKS, 256, 0, stream>>>(col, bukCount);
    f2_bucket_scan<<<1, 256, 0, stream>>>(bukCount, bukBase, bukCursor, offsets);
    f3_scatter<<<F3_BLOCKS, 256, 0, stream>>>(row, col, bukCursor, ebuf);
    f4_finalize<<<NBUK, 256, 0, stream>>>(ebuf, bukBase, offsets, dis, csr_src);

    for (int l = 0; l < 3; ++l) {
        const float* hin = (l == 0) ? x : out;
        gemm_kernel<<<(NN + 63) / 64, 256, 0, stream>>>(hin, Ws + (size_t)l * DD * DD, dis, lin);
        agg_kernel<<<NN / 4, 256, 0, stream>>>(lin, offsets, csr_src, dis, bs + (size_t)l * DD, out);
    }
}

// Round 4
// 427.895 us; speedup vs baseline: 2.9321x; 1.3761x over previous
//
#include <hip/hip_runtime.h>
#include <hip/hip_bf16.h>

#define NN 100000
#define NE 1600000
#define DD 128
#define NBUK 196          // ceil(100000 / 512) buckets of 512 target nodes
#define F1_BLOCKS 256
#define F3_BLOCKS 256

typedef unsigned short ushort_t;
typedef unsigned int uint_t;

__device__ __forceinline__ ushort_t bf16rne(float f) {
    uint_t u = __float_as_uint(f);
    u += 0x7FFF + ((u >> 16) & 1);
    return (ushort_t)(u >> 16);
}
__device__ __forceinline__ float bfLo(uint_t u) { return __uint_as_float(u << 16); }
__device__ __forceinline__ float bfHi(uint_t u) { return __uint_as_float(u & 0xFFFF0000u); }

// ---------------- CSR build (bucketed counting sort) ----------------

__global__ __launch_bounds__(256) void f1_bucket_count(const int* __restrict__ col,
                                                       int* __restrict__ bukCount) {
    __shared__ int hist[NBUK];
    for (int t = threadIdx.x; t < NBUK; t += 256) hist[t] = 0;
    __syncthreads();
    const int epb = (NE + F1_BLOCKS - 1) / F1_BLOCKS;
    const int e0 = blockIdx.x * epb;
    const int e1 = min(e0 + epb, NE);
    for (int e = e0 + threadIdx.x; e < e1; e += 256)
        atomicAdd(&hist[col[e] >> 9], 1);
    __syncthreads();
    for (int t = threadIdx.x; t < NBUK; t += 256)
        if (hist[t]) atomicAdd(&bukCount[t], hist[t]);
}

__global__ void f2_bucket_scan(const int* __restrict__ bukCount,
                               int* __restrict__ bukBase,
                               int* __restrict__ bukCursor,
                               int* __restrict__ offsets) {
    __shared__ int s[256];
    const int t = threadIdx.x;
    int v = (t < NBUK) ? bukCount[t] : 0;
    s[t] = v;
    __syncthreads();
    for (int off = 1; off < 256; off <<= 1) {
        int tmp = (t >= off) ? s[t - off] : 0;
        __syncthreads();
        s[t] += tmp;
        __syncthreads();
    }
    int excl = s[t] - v;
    if (t < NBUK) { bukBase[t] = excl; bukCursor[t] = excl; }
    if (t == 255) { bukBase[NBUK] = s[255]; offsets[NN] = s[255]; }
}

__global__ __launch_bounds__(256) void f3_scatter(const int* __restrict__ row,
                                                  const int* __restrict__ col,
                                                  int* __restrict__ bukCursor,
                                                  int2* __restrict__ ebuf) {
    __shared__ int hist[NBUK];
    __shared__ int base[NBUK];
    __shared__ int rnk[NBUK];
    for (int t = threadIdx.x; t < NBUK; t += 256) { hist[t] = 0; rnk[t] = 0; }
    __syncthreads();
    const int epb = (NE + F3_BLOCKS - 1) / F3_BLOCKS;
    const int e0 = blockIdx.x * epb;
    const int e1 = min(e0 + epb, NE);
    for (int e = e0 + threadIdx.x; e < e1; e += 256)
        atomicAdd(&hist[col[e] >> 9], 1);
    __syncthreads();
    for (int t = threadIdx.x; t < NBUK; t += 256)
        base[t] = hist[t] ? atomicAdd(&bukCursor[t], hist[t]) : 0;
    __syncthreads();
    for (int e = e0 + threadIdx.x; e < e1; e += 256) {
        int c = col[e];
        int b = c >> 9;
        int r = atomicAdd(&rnk[b], 1);
        ebuf[base[b] + r] = make_int2(row[e], c);
    }
}

__global__ __launch_bounds__(256) void f4_finalize(const int2* __restrict__ ebuf,
                                                   const int* __restrict__ bukBase,
                                                   int* __restrict__ offsets,
                                                   float* __restrict__ dis,
                                                   int* __restrict__ csr_src) {
    __shared__ int cnt[512];
    __shared__ int cur[512];
    __shared__ int s[256];
    const int t = threadIdx.x;
    const int colBase = blockIdx.x << 9;
    const int ncols = min(512, NN - colBase);
    cnt[t] = 0; cnt[t + 256] = 0;
    __syncthreads();
    const int eb0 = bukBase[blockIdx.x];
    const int eb1 = bukBase[blockIdx.x + 1];
    for (int e = eb0 + t; e < eb1; e += 256)
        atomicAdd(&cnt[ebuf[e].y - colBase], 1);
    __syncthreads();
    const int c0 = cnt[2 * t], c1 = cnt[2 * t + 1];
    const int psum = c0 + c1;
    s[t] = psum;
    __syncthreads();
    for (int off = 1; off < 256; off <<= 1) {
        int tmp = (t >= off) ? s[t - off] : 0;
        __syncthreads();
        s[t] += tmp;
        __syncthreads();
    }
    const int exclPair = s[t] - psum;
    const int g0 = eb0 + exclPair;
    const int g1 = g0 + c0;
    cur[2 * t] = g0; cur[2 * t + 1] = g1;
    if (2 * t < ncols)     { offsets[colBase + 2 * t]     = g0; dis[colBase + 2 * t]     = rsqrtf((float)(c0 + 1)); }
    if (2 * t + 1 < ncols) { offsets[colBase + 2 * t + 1] = g1; dis[colBase + 2 * t + 1] = rsqrtf((float)(c1 + 1)); }
    __syncthreads();
    for (int e = eb0 + t; e < eb1; e += 256) {
        int2 rc = ebuf[e];
        int p = atomicAdd(&cur[rc.y - colBase], 1);
        csr_src[p] = rc.x;
    }
}

// ---------------- per-layer kernels ----------------

// Y[r][c] = bf16( (sum_k X[r][k] * W[k][c]) * dis[r] )   f32 math, bf16 store
__global__ __launch_bounds__(256) void gemm_kernel(const float* __restrict__ X,
                                                   const float* __restrict__ W,
                                                   const float* __restrict__ dis,
                                                   ushort_t* __restrict__ Y) {
    __shared__ float wlds[DD * DD];  // 64 KB
#pragma unroll
    for (int i = 0; i < 16; ++i) {
        int idx = i * 1024 + threadIdx.x * 4;
        *(float4*)&wlds[idx] = *(const float4*)&W[idx];
    }
    __syncthreads();

    const int tc = threadIdx.x & 15;
    const int tr = threadIdx.x >> 4;
    const int c0 = tc * 8;
    const int r0 = blockIdx.x * 64 + tr * 4;

    float acc[4][8] = {};
    int rr[4];
#pragma unroll
    for (int r = 0; r < 4; ++r) rr[r] = min(r0 + r, NN - 1);

    for (int kk = 0; kk < DD; kk += 4) {
        float xs[4][4];
#pragma unroll
        for (int r = 0; r < 4; ++r) {
            float4 xv = *(const float4*)(X + (size_t)rr[r] * DD + kk);
            xs[r][0] = xv.x; xs[r][1] = xv.y; xs[r][2] = xv.z; xs[r][3] = xv.w;
        }
#pragma unroll
        for (int j = 0; j < 4; ++j) {
            const float* wrow = &wlds[(kk + j) * DD + c0];
            float4 w0 = *(const float4*)wrow;
            float4 w1 = *(const float4*)(wrow + 4);
#pragma unroll
            for (int r = 0; r < 4; ++r) {
                acc[r][0] += xs[r][j] * w0.x;  acc[r][1] += xs[r][j] * w0.y;
                acc[r][2] += xs[r][j] * w0.z;  acc[r][3] += xs[r][j] * w0.w;
                acc[r][4] += xs[r][j] * w1.x;  acc[r][5] += xs[r][j] * w1.y;
                acc[r][6] += xs[r][j] * w1.z;  acc[r][7] += xs[r][j] * w1.w;
            }
        }
    }

#pragma unroll
    for (int r = 0; r < 4; ++r) {
        int row = r0 + r;
        if (row < NN) {
            float dsr = dis[row];
            uint_t p0 = (uint_t)bf16rne(acc[r][0] * dsr) | ((uint_t)bf16rne(acc[r][1] * dsr) << 16);
            uint_t p1 = (uint_t)bf16rne(acc[r][2] * dsr) | ((uint_t)bf16rne(acc[r][3] * dsr) << 16);
            uint_t p2 = (uint_t)bf16rne(acc[r][4] * dsr) | ((uint_t)bf16rne(acc[r][5] * dsr) << 16);
            uint_t p3 = (uint_t)bf16rne(acc[r][6] * dsr) | ((uint_t)bf16rne(acc[r][7] * dsr) << 16);
            uint4 pk = make_uint4(p0, p1, p2, p3);
            *(uint4*)&Y[(size_t)row * DD + c0] = pk;
        }
    }
}

// out[v][d] = relu( dis[v]*( sum_{e in(v)} lin2[src][d] + lin2[v][d] ) + b[d] )
// lin2 is bf16, pre-scaled by dis[src]. One wave per node; lane holds a bf16 pair.
__global__ __launch_bounds__(256) void agg_kernel(const uint_t* __restrict__ lin2,
                                                  const int* __restrict__ offsets,
                                                  const int* __restrict__ csr_src,
                                                  const float* __restrict__ dis,
                                                  const float* __restrict__ bias,
                                                  float* __restrict__ out) {
    const int wave = threadIdx.x >> 6;
    const int lane = threadIdx.x & 63;
    const int v = blockIdx.x * 4 + wave;

    const int start = offsets[v];
    const int end   = offsets[v + 1];
    const int n     = end - start;
    const int nv    = n < 64 ? n : 64;

    int idxv = 0;
    if (lane < nv) idxv = csr_src[start + lane];

    const float dv = dis[v];
    uint_t self = lin2[(size_t)v * 64 + lane];
    float2 b    = ((const float2*)bias)[lane];

    float accx = 0.f, accy = 0.f;
    int k = 0;
    for (; k + 8 <= nv; k += 8) {
        int s0 = __shfl(idxv, k + 0);
        int s1 = __shfl(idxv, k + 1);
        int s2 = __shfl(idxv, k + 2);
        int s3 = __shfl(idxv, k + 3);
        int s4 = __shfl(idxv, k + 4);
        int s5 = __shfl(idxv, k + 5);
        int s6 = __shfl(idxv, k + 6);
        int s7 = __shfl(idxv, k + 7);
        uint_t a0 = lin2[(size_t)s0 * 64 + lane];
        uint_t a1 = lin2[(size_t)s1 * 64 + lane];
        uint_t a2 = lin2[(size_t)s2 * 64 + lane];
        uint_t a3 = lin2[(size_t)s3 * 64 + lane];
        uint_t a4 = lin2[(size_t)s4 * 64 + lane];
        uint_t a5 = lin2[(size_t)s5 * 64 + lane];
        uint_t a6 = lin2[(size_t)s6 * 64 + lane];
        uint_t a7 = lin2[(size_t)s7 * 64 + lane];
        accx += bfLo(a0) + bfLo(a1) + bfLo(a2) + bfLo(a3)
              + bfLo(a4) + bfLo(a5) + bfLo(a6) + bfLo(a7);
        accy += bfHi(a0) + bfHi(a1) + bfHi(a2) + bfHi(a3)
              + bfHi(a4) + bfHi(a5) + bfHi(a6) + bfHi(a7);
    }
    for (; k + 4 <= nv; k += 4) {
        int s0 = __shfl(idxv, k + 0);
        int s1 = __shfl(idxv, k + 1);
        int s2 = __shfl(idxv, k + 2);
        int s3 = __shfl(idxv, k + 3);
        uint_t a0 = lin2[(size_t)s0 * 64 + lane];
        uint_t a1 = lin2[(size_t)s1 * 64 + lane];
        uint_t a2 = lin2[(size_t)s2 * 64 + lane];
        uint_t a3 = lin2[(size_t)s3 * 64 + lane];
        accx += bfLo(a0) + bfLo(a1) + bfLo(a2) + bfLo(a3);
        accy += bfHi(a0) + bfHi(a1) + bfHi(a2) + bfHi(a3);
    }
    for (; k < nv; ++k) {
        int s = __shfl(idxv, k);
        uint_t a = lin2[(size_t)s * 64 + lane];
        accx += bfLo(a); accy += bfHi(a);
    }
    for (int e = start + 64; e < end; ++e) {
        int s = csr_src[e];
        uint_t a = lin2[(size_t)s * 64 + lane];
        accx += bfLo(a); accy += bfHi(a);
    }

    float rx = dv * (accx + bfLo(self)) + b.x;
    float ry = dv * (accy + bfHi(self)) + b.y;
    float2 o;
    o.x = fmaxf(rx, 0.f);
    o.y = fmaxf(ry, 0.f);
    ((float2*)out)[(size_t)v * 64 + lane] = o;
}

// ---------------- launch ----------------

extern "C" void kernel_launch(void* const* d_in, const int* in_sizes, int n_in,
                              void* d_out, int out_size, void* d_ws, size_t ws_size,
                              hipStream_t stream) {
    const float* x   = (const float*)d_in[0];
    const int*   ei  = (const int*)d_in[1];
    const float* Ws  = (const float*)d_in[2];
    const float* bs  = (const float*)d_in[3];
    float* out = (float*)d_out;

    const int* row = ei;
    const int* col = ei + NE;

    char* ws = (char*)d_ws;
    ushort_t* lin    = (ushort_t*)(ws + 0);       // 12.8M bf16 = 25,600,000 B (ebuf aliases)
    int2*  ebuf      = (int2*) (ws + 0);          // 12,800,000 B (dead before gemm)
    float* dis       = (float*)(ws + 51200000);
    int*   offsets   = (int*)  (ws + 51600000);
    int*   csr_src   = (int*)  (ws + 52000016);
    int*   bukCount  = (int*)  (ws + 58400016);
    int*   bukBase   = (int*)  (ws + 58400800);
    int*   bukCursor = (int*)  (ws + 58401600);

    hipMemsetAsync(bukCount, 0, NBUK * sizeof(int), stream);
    f1_bucket_count<<<F1_BLOCKS, 256, 0, stream>>>(col, bukCount);
    f2_bucket_scan<<<1, 256, 0, stream>>>(bukCount, bukBase, bukCursor, offsets);
    f3_scatter<<<F3_BLOCKS, 256, 0, stream>>>(row, col, bukCursor, ebuf);
    f4_finalize<<<NBUK, 256, 0, stream>>>(ebuf, bukBase, offsets, dis, csr_src);

    for (int l = 0; l < 3; ++l) {
        const float* hin = (l == 0) ? x : out;
        gemm_kernel<<<(NN + 63) / 64, 256, 0, stream>>>(hin, Ws + (size_t)l * DD * DD, dis, lin);
        agg_kernel<<<NN / 4, 256, 0, stream>>>((const uint_t*)lin, offsets, csr_src, dis,
                                               bs + (size_t)l * DD, out);
    }
}

// Round 5
// 306.068 us; speedup vs baseline: 4.0992x; 1.3980x over previous
//
#include <hip/hip_runtime.h>
#include <hip/hip_bf16.h>

#define NN 100000
#define NE 1600000
#define DD 128
#define NBUK 196          // ceil(100000 / 512) buckets of 512 target nodes
#define F1_BLOCKS 256
#define F3_BLOCKS 256

typedef unsigned short ushort_t;
typedef unsigned int uint_t;
typedef __attribute__((ext_vector_type(8))) short bf16x8;
typedef __attribute__((ext_vector_type(4))) float f32x4;

__device__ __forceinline__ ushort_t bf16rne(float f) {
    uint_t u = __float_as_uint(f);
    u += 0x7FFF + ((u >> 16) & 1);
    return (ushort_t)(u >> 16);
}
__device__ __forceinline__ float bfLo(uint_t u) { return __uint_as_float(u << 16); }
__device__ __forceinline__ float bfHi(uint_t u) { return __uint_as_float(u & 0xFFFF0000u); }

// ---------------- CSR build (bucketed counting sort) ----------------

__global__ __launch_bounds__(256) void f1_bucket_count(const int* __restrict__ col,
                                                       int* __restrict__ bukCount) {
    __shared__ int hist[NBUK];
    for (int t = threadIdx.x; t < NBUK; t += 256) hist[t] = 0;
    __syncthreads();
    const int epb = (NE + F1_BLOCKS - 1) / F1_BLOCKS;
    const int e0 = blockIdx.x * epb;
    const int e1 = min(e0 + epb, NE);
    for (int e = e0 + threadIdx.x; e < e1; e += 256)
        atomicAdd(&hist[col[e] >> 9], 1);
    __syncthreads();
    for (int t = threadIdx.x; t < NBUK; t += 256)
        if (hist[t]) atomicAdd(&bukCount[t], hist[t]);
}

__global__ void f2_bucket_scan(const int* __restrict__ bukCount,
                               int* __restrict__ bukBase,
                               int* __restrict__ bukCursor,
                               int* __restrict__ offsets) {
    __shared__ int s[256];
    const int t = threadIdx.x;
    int v = (t < NBUK) ? bukCount[t] : 0;
    s[t] = v;
    __syncthreads();
    for (int off = 1; off < 256; off <<= 1) {
        int tmp = (t >= off) ? s[t - off] : 0;
        __syncthreads();
        s[t] += tmp;
        __syncthreads();
    }
    int excl = s[t] - v;
    if (t < NBUK) { bukBase[t] = excl; bukCursor[t] = excl; }
    if (t == 255) { bukBase[NBUK] = s[255]; offsets[NN] = s[255]; }
}

__global__ __launch_bounds__(256) void f3_scatter(const int* __restrict__ row,
                                                  const int* __restrict__ col,
                                                  int* __restrict__ bukCursor,
                                                  int2* __restrict__ ebuf) {
    __shared__ int hist[NBUK];
    __shared__ int base[NBUK];
    __shared__ int rnk[NBUK];
    for (int t = threadIdx.x; t < NBUK; t += 256) { hist[t] = 0; rnk[t] = 0; }
    __syncthreads();
    const int epb = (NE + F3_BLOCKS - 1) / F3_BLOCKS;
    const int e0 = blockIdx.x * epb;
    const int e1 = min(e0 + epb, NE);
    for (int e = e0 + threadIdx.x; e < e1; e += 256)
        atomicAdd(&hist[col[e] >> 9], 1);
    __syncthreads();
    for (int t = threadIdx.x; t < NBUK; t += 256)
        base[t] = hist[t] ? atomicAdd(&bukCursor[t], hist[t]) : 0;
    __syncthreads();
    for (int e = e0 + threadIdx.x; e < e1; e += 256) {
        int c = col[e];
        int b = c >> 9;
        int r = atomicAdd(&rnk[b], 1);
        ebuf[base[b] + r] = make_int2(row[e], c);
    }
}

__global__ __launch_bounds__(256) void f4_finalize(const int2* __restrict__ ebuf,
                                                   const int* __restrict__ bukBase,
                                                   int* __restrict__ offsets,
                                                   float* __restrict__ dis,
                                                   int* __restrict__ csr_src) {
    __shared__ int cnt[512];
    __shared__ int cur[512];
    __shared__ int s[256];
    const int t = threadIdx.x;
    const int colBase = blockIdx.x << 9;
    const int ncols = min(512, NN - colBase);
    cnt[t] = 0; cnt[t + 256] = 0;
    __syncthreads();
    const int eb0 = bukBase[blockIdx.x];
    const int eb1 = bukBase[blockIdx.x + 1];
    for (int e = eb0 + t; e < eb1; e += 256)
        atomicAdd(&cnt[ebuf[e].y - colBase], 1);
    __syncthreads();
    const int c0 = cnt[2 * t], c1 = cnt[2 * t + 1];
    const int psum = c0 + c1;
    s[t] = psum;
    __syncthreads();
    for (int off = 1; off < 256; off <<= 1) {
        int tmp = (t >= off) ? s[t - off] : 0;
        __syncthreads();
        s[t] += tmp;
        __syncthreads();
    }
    const int exclPair = s[t] - psum;
    const int g0 = eb0 + exclPair;
    const int g1 = g0 + c0;
    cur[2 * t] = g0; cur[2 * t + 1] = g1;
    if (2 * t < ncols)     { offsets[colBase + 2 * t]     = g0; dis[colBase + 2 * t]     = rsqrtf((float)(c0 + 1)); }
    if (2 * t + 1 < ncols) { offsets[colBase + 2 * t + 1] = g1; dis[colBase + 2 * t + 1] = rsqrtf((float)(c1 + 1)); }
    __syncthreads();
    for (int e = eb0 + t; e < eb1; e += 256) {
        int2 rc = ebuf[e];
        int p = atomicAdd(&cur[rc.y - colBase], 1);
        csr_src[p] = rc.x;
    }
}

// ---------------- W prep: bf16 + transpose wT[l][col][k] ----------------

__global__ __launch_bounds__(256) void wt_kernel(const float* __restrict__ Ws,
                                                 ushort_t* __restrict__ wT) {
    int idx = blockIdx.x * 256 + threadIdx.x;   // 0..6143
    if (idx >= 3 * 128 * 16) return;
    int l = idx >> 11;            // /2048
    int r = idx & 2047;
    int c = r >> 4;               // col 0..127
    int kc = r & 15;              // 8-wide k-chunk
    const float* w = Ws + l * 16384;
    ushort_t tmp[8];
#pragma unroll
    for (int e = 0; e < 8; ++e)
        tmp[e] = bf16rne(w[(kc * 8 + e) * 128 + c]);
    *(uint4*)&wT[(size_t)l * 16384 + c * 128 + kc * 8] = *(uint4*)tmp;
}

// ---------------- MFMA GEMM: Y[r][c] = bf16( (X@W)[r][c] * dis[r] ) ----------------
// Block = 4 waves x 16 rows = 64 rows. W^T staged in LDS (136-short padded rows).

template<bool XF32>
__global__ __launch_bounds__(256) void gemm_mfma(const void* __restrict__ Xv,
                                                 const ushort_t* __restrict__ wT,
                                                 const float* __restrict__ dis,
                                                 ushort_t* __restrict__ Y) {
    __shared__ short wlds[128 * 136];   // 34.8 KB
    {
        const uint4* src = (const uint4*)wT;   // 2048 uint4
        int t = threadIdx.x;
#pragma unroll
        for (int i = 0; i < 8; ++i) {
            int idx = i * 256 + t;
            int rowc = idx >> 4;      // col 0..127
            int kc = idx & 15;
            uint4 v = src[idx];
            *(uint4*)&wlds[rowc * 136 + kc * 8] = v;
        }
    }
    __syncthreads();

    const int wave = threadIdx.x >> 6;
    const int lane = threadIdx.x & 63;
    const int m = lane & 15;
    const int kg = lane >> 4;                 // 0..3
    const int r0 = blockIdx.x * 64 + wave * 16;
    const int rowA = min(r0 + m, NN - 1);

    f32x4 acc[8];
#pragma unroll
    for (int ct = 0; ct < 8; ++ct) acc[ct] = (f32x4){0.f, 0.f, 0.f, 0.f};

#pragma unroll
    for (int ks = 0; ks < 4; ++ks) {
        bf16x8 af;
        if (XF32) {
            const float* xp = (const float*)Xv + (size_t)rowA * DD + ks * 32 + kg * 8;
            float4 f0 = *(const float4*)xp;
            float4 f1 = *(const float4*)(xp + 4);
            af[0] = (short)bf16rne(f0.x); af[1] = (short)bf16rne(f0.y);
            af[2] = (short)bf16rne(f0.z); af[3] = (short)bf16rne(f0.w);
            af[4] = (short)bf16rne(f1.x); af[5] = (short)bf16rne(f1.y);
            af[6] = (short)bf16rne(f1.z); af[7] = (short)bf16rne(f1.w);
        } else {
            const ushort_t* xp = (const ushort_t*)Xv + (size_t)rowA * DD + ks * 32 + kg * 8;
            af = *(const bf16x8*)xp;
        }
#pragma unroll
        for (int ct = 0; ct < 8; ++ct) {
            bf16x8 bf = *(const bf16x8*)&wlds[(ct * 16 + m) * 136 + ks * 32 + kg * 8];
            acc[ct] = __builtin_amdgcn_mfma_f32_16x16x32_bf16(af, bf, acc[ct], 0, 0, 0);
        }
    }

    // C/D: col = ct*16 + (lane&15), row = (lane>>4)*4 + reg   [m89-verified]
    const int rbase = r0 + kg * 4;
    float dv[4];
#pragma unroll
    for (int rg = 0; rg < 4; ++rg) dv[rg] = dis[min(rbase + rg, NN - 1)];
#pragma unroll
    for (int ct = 0; ct < 8; ++ct) {
#pragma unroll
        for (int rg = 0; rg < 4; ++rg) {
            int row = rbase + rg;
            if (row < NN)
                Y[(size_t)row * DD + ct * 16 + m] = bf16rne(acc[ct][rg] * dv[rg]);
        }
    }
}

// ---------------- aggregation ----------------
// out[v][d] = relu( dis[v]*( sum_in lin2[src][d] + lin2[v][d] ) + b[d] )

template<bool F32OUT>
__global__ __launch_bounds__(256) void agg_kernel(const uint_t* __restrict__ lin2,
                                                  const int* __restrict__ offsets,
                                                  const int* __restrict__ csr_src,
                                                  const float* __restrict__ dis,
                                                  const float* __restrict__ bias,
                                                  void* __restrict__ outv) {
    const int wave = threadIdx.x >> 6;
    const int lane = threadIdx.x & 63;
    const int v = blockIdx.x * 4 + wave;

    const int start = offsets[v];
    const int end   = offsets[v + 1];
    const int n     = end - start;
    const int nv    = n < 64 ? n : 64;

    int idxv = 0;
    if (lane < nv) idxv = csr_src[start + lane];

    const float dv = dis[v];
    uint_t self = lin2[(size_t)v * 64 + lane];
    float2 b    = ((const float2*)bias)[lane];

    float accx = 0.f, accy = 0.f;
    int k = 0;
    for (; k + 8 <= nv; k += 8) {
        int s0 = __shfl(idxv, k + 0);
        int s1 = __shfl(idxv, k + 1);
        int s2 = __shfl(idxv, k + 2);
        int s3 = __shfl(idxv, k + 3);
        int s4 = __shfl(idxv, k + 4);
        int s5 = __shfl(idxv, k + 5);
        int s6 = __shfl(idxv, k + 6);
        int s7 = __shfl(idxv, k + 7);
        uint_t a0 = lin2[(size_t)s0 * 64 + lane];
        uint_t a1 = lin2[(size_t)s1 * 64 + lane];
        uint_t a2 = lin2[(size_t)s2 * 64 + lane];
        uint_t a3 = lin2[(size_t)s3 * 64 + lane];
        uint_t a4 = lin2[(size_t)s4 * 64 + lane];
        uint_t a5 = lin2[(size_t)s5 * 64 + lane];
        uint_t a6 = lin2[(size_t)s6 * 64 + lane];
        uint_t a7 = lin2[(size_t)s7 * 64 + lane];
        accx += bfLo(a0) + bfLo(a1) + bfLo(a2) + bfLo(a3)
              + bfLo(a4) + bfLo(a5) + bfLo(a6) + bfLo(a7);
        accy += bfHi(a0) + bfHi(a1) + bfHi(a2) + bfHi(a3)
              + bfHi(a4) + bfHi(a5) + bfHi(a6) + bfHi(a7);
    }
    for (; k + 4 <= nv; k += 4) {
        int s0 = __shfl(idxv, k + 0);
        int s1 = __shfl(idxv, k + 1);
        int s2 = __shfl(idxv, k + 2);
        int s3 = __shfl(idxv, k + 3);
        uint_t a0 = lin2[(size_t)s0 * 64 + lane];
        uint_t a1 = lin2[(size_t)s1 * 64 + lane];
        uint_t a2 = lin2[(size_t)s2 * 64 + lane];
        uint_t a3 = lin2[(size_t)s3 * 64 + lane];
        accx += bfLo(a0) + bfLo(a1) + bfLo(a2) + bfLo(a3);
        accy += bfHi(a0) + bfHi(a1) + bfHi(a2) + bfHi(a3);
    }
    for (; k < nv; ++k) {
        int s = __shfl(idxv, k);
        uint_t a = lin2[(size_t)s * 64 + lane];
        accx += bfLo(a); accy += bfHi(a);
    }
    for (int e = start + 64; e < end; ++e) {
        int s = csr_src[e];
        uint_t a = lin2[(size_t)s * 64 + lane];
        accx += bfLo(a); accy += bfHi(a);
    }

    float rx = fmaxf(dv * (accx + bfLo(self)) + b.x, 0.f);
    float ry = fmaxf(dv * (accy + bfHi(self)) + b.y, 0.f);
    if (F32OUT) {
        ((float2*)outv)[(size_t)v * 64 + lane] = make_float2(rx, ry);
    } else {
        uint_t pk = (uint_t)bf16rne(rx) | ((uint_t)bf16rne(ry) << 16);
        ((uint_t*)outv)[(size_t)v * 64 + lane] = pk;
    }
}

// ---------------- launch ----------------

extern "C" void kernel_launch(void* const* d_in, const int* in_sizes, int n_in,
                              void* d_out, int out_size, void* d_ws, size_t ws_size,
                              hipStream_t stream) {
    const float* x   = (const float*)d_in[0];
    const int*   ei  = (const int*)d_in[1];
    const float* Ws  = (const float*)d_in[2];
    const float* bs  = (const float*)d_in[3];

    const int* row = ei;
    const int* col = ei + NE;

    char* ws = (char*)d_ws;
    ushort_t* lin    = (ushort_t*)(ws + 0);       // 25,600,000 B (ebuf aliases low half)
    int2*  ebuf      = (int2*) (ws + 0);          // 12,800,000 B (dead after f4)
    ushort_t* hb     = (ushort_t*)(ws + 25600000);// 25,600,000 B bf16 inter-layer h
    float* dis       = (float*)(ws + 51200000);
    int*   offsets   = (int*)  (ws + 51600000);
    int*   csr_src   = (int*)  (ws + 52000016);
    int*   bukCount  = (int*)  (ws + 58400016);
    int*   bukBase   = (int*)  (ws + 58400800);
    int*   bukCursor = (int*)  (ws + 58401600);
    ushort_t* wT     = (ushort_t*)(ws + 58402432);// 98,304 B

    hipMemsetAsync(bukCount, 0, NBUK * sizeof(int), stream);
    f1_bucket_count<<<F1_BLOCKS, 256, 0, stream>>>(col, bukCount);
    f2_bucket_scan<<<1, 256, 0, stream>>>(bukCount, bukBase, bukCursor, offsets);
    f3_scatter<<<F3_BLOCKS, 256, 0, stream>>>(row, col, bukCursor, ebuf);
    f4_finalize<<<NBUK, 256, 0, stream>>>(ebuf, bukBase, offsets, dis, csr_src);
    wt_kernel<<<24, 256, 0, stream>>>(Ws, wT);

    const int gemmGrid = (NN + 63) / 64;
    // layer 0: f32 x -> lin ; agg -> bf16 hb
    gemm_mfma<true><<<gemmGrid, 256, 0, stream>>>(x, wT, dis, lin);
    agg_kernel<false><<<NN / 4, 256, 0, stream>>>((const uint_t*)lin, offsets, csr_src, dis, bs, hb);
    // layer 1: bf16 hb -> lin ; agg -> bf16 hb
    gemm_mfma<false><<<gemmGrid, 256, 0, stream>>>(hb, wT + 16384, dis, lin);
    agg_kernel<false><<<NN / 4, 256, 0, stream>>>((const uint_t*)lin, offsets, csr_src, dis, bs + DD, hb);
    // layer 2: bf16 hb -> lin ; agg -> f32 d_out
    gemm_mfma<false><<<gemmGrid, 256, 0, stream>>>(hb, wT + 32768, dis, lin);
    agg_kernel<true><<<NN / 4, 256, 0, stream>>>((const uint_t*)lin, offsets, csr_src, dis, bs + 2 * DD, d_out);
}

// Round 6
// 291.884 us; speedup vs baseline: 4.2984x; 1.0486x over previous
//
#include <hip/hip_runtime.h>
#include <hip/hip_bf16.h>

#define NN 100000
#define NE 1600000
#define DD 128
#define NBUK 196          // ceil(100000 / 512) buckets of 512 target nodes
#define F1_BLOCKS 256
#define F3_BLOCKS 256

typedef unsigned short ushort_t;
typedef unsigned int uint_t;
typedef __attribute__((ext_vector_type(8))) short bf16x8;
typedef __attribute__((ext_vector_type(4))) float f32x4;

__device__ __forceinline__ ushort_t bf16rne(float f) {
    uint_t u = __float_as_uint(f);
    u += 0x7FFF + ((u >> 16) & 1);
    return (ushort_t)(u >> 16);
}
__device__ __forceinline__ float bfLo(uint_t u) { return __uint_as_float(u << 16); }
__device__ __forceinline__ float bfHi(uint_t u) { return __uint_as_float(u & 0xFFFF0000u); }

// ---------------- CSR build (bucketed counting sort) ----------------

__global__ __launch_bounds__(256) void f1_bucket_count(const int* __restrict__ col,
                                                       int* __restrict__ bukCount) {
    __shared__ int hist[NBUK];
    for (int t = threadIdx.x; t < NBUK; t += 256) hist[t] = 0;
    __syncthreads();
    const int epb = (NE + F1_BLOCKS - 1) / F1_BLOCKS;
    const int e0 = blockIdx.x * epb;
    const int e1 = min(e0 + epb, NE);
    for (int e = e0 + threadIdx.x; e < e1; e += 256)
        atomicAdd(&hist[col[e] >> 9], 1);
    __syncthreads();
    for (int t = threadIdx.x; t < NBUK; t += 256)
        if (hist[t]) atomicAdd(&bukCount[t], hist[t]);
}

__global__ void f2_bucket_scan(const int* __restrict__ bukCount,
                               int* __restrict__ bukBase,
                               int* __restrict__ bukCursor,
                               int* __restrict__ offsets) {
    __shared__ int s[256];
    const int t = threadIdx.x;
    int v = (t < NBUK) ? bukCount[t] : 0;
    s[t] = v;
    __syncthreads();
    for (int off = 1; off < 256; off <<= 1) {
        int tmp = (t >= off) ? s[t - off] : 0;
        __syncthreads();
        s[t] += tmp;
        __syncthreads();
    }
    int excl = s[t] - v;
    if (t < NBUK) { bukBase[t] = excl; bukCursor[t] = excl; }
    if (t == 255) { bukBase[NBUK] = s[255]; offsets[NN] = s[255]; }
}

// per-wave LDS histograms (4x less contention); ebuf packed as (row<<9)|col_local
__global__ __launch_bounds__(256) void f3_scatter(const int* __restrict__ row,
                                                  const int* __restrict__ col,
                                                  int* __restrict__ bukCursor,
                                                  int* __restrict__ ebuf) {
    __shared__ int hist[4][NBUK];   // reused as rank counters after base claim
    __shared__ int base[4][NBUK];
    const int t = threadIdx.x;
    const int w = t >> 6;
    const int lane = t & 63;
    for (int i = t; i < 4 * NBUK; i += 256) (&hist[0][0])[i] = 0;
    __syncthreads();
    const int epb = (NE + F3_BLOCKS - 1) / F3_BLOCKS;     // 6250
    const int e0 = blockIdx.x * epb;
    const int e1 = min(e0 + epb, NE);
    const int wepb = (e1 - e0 + 3) >> 2;
    const int we0 = e0 + w * wepb;
    const int we1 = min(we0 + wepb, e1);
    for (int e = we0 + lane; e < we1; e += 64)
        atomicAdd(&hist[w][col[e] >> 9], 1);
    __syncthreads();
    if (t < NBUK) {
        int h0 = hist[0][t], h1 = hist[1][t], h2 = hist[2][t], h3 = hist[3][t];
        int tot = h0 + h1 + h2 + h3;
        int g = tot ? atomicAdd(&bukCursor[t], tot) : 0;
        base[0][t] = g; base[1][t] = g + h0;
        base[2][t] = g + h0 + h1; base[3][t] = g + h0 + h1 + h2;
        hist[0][t] = 0; hist[1][t] = 0; hist[2][t] = 0; hist[3][t] = 0;
    }
    __syncthreads();
    for (int e = we0 + lane; e < we1; e += 64) {
        int c = col[e];
        int b = c >> 9;
        int r = atomicAdd(&hist[w][b], 1);
        ebuf[base[w][b] + r] = (row[e] << 9) | (c & 511);
    }
}

__global__ __launch_bounds__(256) void f4_finalize(const int* __restrict__ ebuf,
                                                   const int* __restrict__ bukBase,
                                                   int* __restrict__ offsets,
                                                   float* __restrict__ dis,
                                                   int* __restrict__ csr_src) {
    __shared__ int cnt[512];
    __shared__ int cur[512];
    __shared__ int s[256];
    const int t = threadIdx.x;
    const int colBase = blockIdx.x << 9;
    const int ncols = min(512, NN - colBase);
    cnt[t] = 0; cnt[t + 256] = 0;
    __syncthreads();
    const int eb0 = bukBase[blockIdx.x];
    const int eb1 = bukBase[blockIdx.x + 1];
    for (int e = eb0 + t; e < eb1; e += 256)
        atomicAdd(&cnt[ebuf[e] & 511], 1);
    __syncthreads();
    const int c0 = cnt[2 * t], c1 = cnt[2 * t + 1];
    const int psum = c0 + c1;
    s[t] = psum;
    __syncthreads();
    for (int off = 1; off < 256; off <<= 1) {
        int tmp = (t >= off) ? s[t - off] : 0;
        __syncthreads();
        s[t] += tmp;
        __syncthreads();
    }
    const int exclPair = s[t] - psum;
    const int g0 = eb0 + exclPair;
    const int g1 = g0 + c0;
    cur[2 * t] = g0; cur[2 * t + 1] = g1;
    if (2 * t < ncols)     { offsets[colBase + 2 * t]     = g0; dis[colBase + 2 * t]     = rsqrtf((float)(c0 + 1)); }
    if (2 * t + 1 < ncols) { offsets[colBase + 2 * t + 1] = g1; dis[colBase + 2 * t + 1] = rsqrtf((float)(c1 + 1)); }
    __syncthreads();
    for (int e = eb0 + t; e < eb1; e += 256) {
        int pc = ebuf[e];
        int p = atomicAdd(&cur[pc & 511], 1);
        csr_src[p] = pc >> 9;
    }
}

// ---------------- W prep: bf16 + transpose wT[l][col][k] ----------------

__global__ __launch_bounds__(256) void wt_kernel(const float* __restrict__ Ws,
                                                 ushort_t* __restrict__ wT) {
    int idx = blockIdx.x * 256 + threadIdx.x;   // 0..6143
    if (idx >= 3 * 128 * 16) return;
    int l = idx >> 11;
    int r = idx & 2047;
    int c = r >> 4;
    int kc = r & 15;
    const float* w = Ws + l * 16384;
    ushort_t tmp[8];
#pragma unroll
    for (int e = 0; e < 8; ++e)
        tmp[e] = bf16rne(w[(kc * 8 + e) * 128 + c]);
    *(uint4*)&wT[(size_t)l * 16384 + c * 128 + kc * 8] = *(uint4*)tmp;
}

// ---------------- MFMA GEMM: Y[r][c] = bf16( (X@W)[r][c] * dis[r] ) ----------------

template<bool XF32>
__global__ __launch_bounds__(256) void gemm_mfma(const void* __restrict__ Xv,
                                                 const ushort_t* __restrict__ wT,
                                                 const float* __restrict__ dis,
                                                 ushort_t* __restrict__ Y) {
    __shared__ short wlds[128 * 136];   // 34.8 KB
    {
        const uint4* src = (const uint4*)wT;
        int t = threadIdx.x;
#pragma unroll
        for (int i = 0; i < 8; ++i) {
            int idx = i * 256 + t;
            int rowc = idx >> 4;
            int kc = idx & 15;
            uint4 v = src[idx];
            *(uint4*)&wlds[rowc * 136 + kc * 8] = v;
        }
    }
    __syncthreads();

    const int wave = threadIdx.x >> 6;
    const int lane = threadIdx.x & 63;
    const int m = lane & 15;
    const int kg = lane >> 4;
    const int r0 = blockIdx.x * 64 + wave * 16;
    const int rowA = min(r0 + m, NN - 1);

    f32x4 acc[8];
#pragma unroll
    for (int ct = 0; ct < 8; ++ct) acc[ct] = (f32x4){0.f, 0.f, 0.f, 0.f};

#pragma unroll
    for (int ks = 0; ks < 4; ++ks) {
        bf16x8 af;
        if (XF32) {
            const float* xp = (const float*)Xv + (size_t)rowA * DD + ks * 32 + kg * 8;
            float4 f0 = *(const float4*)xp;
            float4 f1 = *(const float4*)(xp + 4);
            af[0] = (short)bf16rne(f0.x); af[1] = (short)bf16rne(f0.y);
            af[2] = (short)bf16rne(f0.z); af[3] = (short)bf16rne(f0.w);
            af[4] = (short)bf16rne(f1.x); af[5] = (short)bf16rne(f1.y);
            af[6] = (short)bf16rne(f1.z); af[7] = (short)bf16rne(f1.w);
        } else {
            const ushort_t* xp = (const ushort_t*)Xv + (size_t)rowA * DD + ks * 32 + kg * 8;
            af = *(const bf16x8*)xp;
        }
#pragma unroll
        for (int ct = 0; ct < 8; ++ct) {
            bf16x8 bf = *(const bf16x8*)&wlds[(ct * 16 + m) * 136 + ks * 32 + kg * 8];
            acc[ct] = __builtin_amdgcn_mfma_f32_16x16x32_bf16(af, bf, acc[ct], 0, 0, 0);
        }
    }

    const int rbase = r0 + kg * 4;
    float dv[4];
#pragma unroll
    for (int rg = 0; rg < 4; ++rg) dv[rg] = dis[min(rbase + rg, NN - 1)];
#pragma unroll
    for (int ct = 0; ct < 8; ++ct) {
#pragma unroll
        for (int rg = 0; rg < 4; ++rg) {
            int row = rbase + rg;
            if (row < NN)
                Y[(size_t)row * DD + ct * 16 + m] = bf16rne(acc[ct][rg] * dv[rg]);
        }
    }
}

// ---------------- aggregation (XCD-aware D-split) ----------------
// Block = 4 waves; wave = 2 nodes x 64 dims (one D-half).
// blockIdx%8 -> XCD (heuristic): halves 0/1 pinned to XCD groups 0-3 / 4-7,
// so each XCD gathers from a 12.8 MB slice of lin (vs 25.6 full).

template<bool F32OUT>
__global__ __launch_bounds__(256) void agg_kernel(const uint_t* __restrict__ lin2,
                                                  const int* __restrict__ offsets,
                                                  const int* __restrict__ csr_src,
                                                  const float* __restrict__ dis,
                                                  const float* __restrict__ bias,
                                                  void* __restrict__ outv) {
    const int bid = blockIdx.x;                 // 25000 blocks
    const int xcd = bid & 7;
    const int h   = (xcd >> 2);                 // D-half 0/1
    const int g   = (bid >> 3) * 4 + (xcd & 3); // node-group of 8, in [0,12500)
    const int w    = threadIdx.x >> 6;
    const int lane = threadIdx.x & 63;
    const int l32  = lane & 31;
    const int hi   = lane >> 5;                 // which of the wave's 2 nodes
    const int v = g * 8 + w * 2 + hi;

    const int start = offsets[v];
    const int end   = offsets[v + 1];
    const int n     = end - start;
    const int nvm   = n < 32 ? n : 32;

    int idxv = 0;
    if (l32 < nvm) idxv = csr_src[start + l32];

    // wave-uniform loop bound = max of the two nodes' (clamped) degrees
    const int nv_other = __shfl(nvm, lane ^ 32);
    const int kmax = nvm > nv_other ? nvm : nv_other;

    const int doff = h * 32 + l32;              // uint index within row (64 uints/row)
    const float dv = dis[v];
    uint_t self = lin2[(size_t)v * 64 + doff];
    float2 b    = ((const float2*)bias)[doff];

    float accx = 0.f, accy = 0.f;
    const int sbase = (lane & 32);
    for (int k = 0; k < kmax; k += 8) {
        int s0 = __shfl(idxv, sbase + k + 0);
        int s1 = __shfl(idxv, sbase + k + 1);
        int s2 = __shfl(idxv, sbase + k + 2);
        int s3 = __shfl(idxv, sbase + k + 3);
        int s4 = __shfl(idxv, sbase + k + 4);
        int s5 = __shfl(idxv, sbase + k + 5);
        int s6 = __shfl(idxv, sbase + k + 6);
        int s7 = __shfl(idxv, sbase + k + 7);
        uint_t a0 = lin2[(size_t)s0 * 64 + doff];
        uint_t a1 = lin2[(size_t)s1 * 64 + doff];
        uint_t a2 = lin2[(size_t)s2 * 64 + doff];
        uint_t a3 = lin2[(size_t)s3 * 64 + doff];
        uint_t a4 = lin2[(size_t)s4 * 64 + doff];
        uint_t a5 = lin2[(size_t)s5 * 64 + doff];
        uint_t a6 = lin2[(size_t)s6 * 64 + doff];
        uint_t a7 = lin2[(size_t)s7 * 64 + doff];
        if (k + 0 < nvm) { accx += bfLo(a0); accy += bfHi(a0); }
        if (k + 1 < nvm) { accx += bfLo(a1); accy += bfHi(a1); }
        if (k + 2 < nvm) { accx += bfLo(a2); accy += bfHi(a2); }
        if (k + 3 < nvm) { accx += bfLo(a3); accy += bfHi(a3); }
        if (k + 4 < nvm) { accx += bfLo(a4); accy += bfHi(a4); }
        if (k + 5 < nvm) { accx += bfLo(a5); accy += bfHi(a5); }
        if (k + 6 < nvm) { accx += bfLo(a6); accy += bfHi(a6); }
        if (k + 7 < nvm) { accx += bfLo(a7); accy += bfHi(a7); }
    }
    // rare deg>32 tail
    for (int e = start + 32; e < end; ++e) {
        int s = csr_src[e];
        uint_t a = lin2[(size_t)s * 64 + doff];
        accx += bfLo(a); accy += bfHi(a);
    }

    float rx = fmaxf(dv * (accx + bfLo(self)) + b.x, 0.f);
    float ry = fmaxf(dv * (accy + bfHi(self)) + b.y, 0.f);
    const size_t oidx = (size_t)v * 64 + doff;
    if (F32OUT) {
        float2 o = make_float2(rx, ry);
        __builtin_nontemporal_store(*(const double*)&o, (double*)((float2*)outv + oidx));
    } else {
        uint_t pk = (uint_t)bf16rne(rx) | ((uint_t)bf16rne(ry) << 16);
        __builtin_nontemporal_store(pk, (uint_t*)outv + oidx);
    }
}

// ---------------- launch ----------------

extern "C" void kernel_launch(void* const* d_in, const int* in_sizes, int n_in,
                              void* d_out, int out_size, void* d_ws, size_t ws_size,
                              hipStream_t stream) {
    const float* x   = (const float*)d_in[0];
    const int*   ei  = (const int*)d_in[1];
    const float* Ws  = (const float*)d_in[2];
    const float* bs  = (const float*)d_in[3];

    const int* row = ei;
    const int* col = ei + NE;

    char* ws = (char*)d_ws;
    ushort_t* lin    = (ushort_t*)(ws + 0);       // 25,600,000 B (ebuf aliases low part)
    int*   ebuf      = (int*)  (ws + 0);          // 6,400,000 B packed (dead after f4)
    ushort_t* hb     = (ushort_t*)(ws + 25600000);// 25,600,000 B bf16 inter-layer h
    float* dis       = (float*)(ws + 51200000);
    int*   offsets   = (int*)  (ws + 51600000);
    int*   csr_src   = (int*)  (ws + 52000016);
    int*   bukCount  = (int*)  (ws + 58400016);
    int*   bukBase   = (int*)  (ws + 58400800);
    int*   bukCursor = (int*)  (ws + 58401600);
    ushort_t* wT     = (ushort_t*)(ws + 58402432);// 98,304 B

    hipMemsetAsync(bukCount, 0, NBUK * sizeof(int), stream);
    f1_bucket_count<<<F1_BLOCKS, 256, 0, stream>>>(col, bukCount);
    f2_bucket_scan<<<1, 256, 0, stream>>>(bukCount, bukBase, bukCursor, offsets);
    f3_scatter<<<F3_BLOCKS, 256, 0, stream>>>(row, col, bukCursor, ebuf);
    f4_finalize<<<NBUK, 256, 0, stream>>>(ebuf, bukBase, offsets, dis, csr_src);
    wt_kernel<<<24, 256, 0, stream>>>(Ws, wT);

    const int gemmGrid = (NN + 63) / 64;
    const int aggGrid = (NN / 8) * 2;   // 25000
    // layer 0: f32 x -> lin ; agg -> bf16 hb
    gemm_mfma<true><<<gemmGrid, 256, 0, stream>>>(x, wT, dis, lin);
    agg_kernel<false><<<aggGrid, 256, 0, stream>>>((const uint_t*)lin, offsets, csr_src, dis, bs, hb);
    // layer 1
    gemm_mfma<false><<<gemmGrid, 256, 0, stream>>>(hb, wT + 16384, dis, lin);
    agg_kernel<false><<<aggGrid, 256, 0, stream>>>((const uint_t*)lin, offsets, csr_src, dis, bs + DD, hb);
    // layer 2 -> f32 d_out
    gemm_mfma<false><<<gemmGrid, 256, 0, stream>>>(hb, wT + 32768, dis, lin);
    agg_kernel<true><<<aggGrid, 256, 0, stream>>>((const uint_t*)lin, offsets, csr_src, dis, bs + 2 * DD, d_out);
}